// Round 3
// baseline (213.409 us; speedup 1.0000x reference)
//
#include <hip/hip_runtime.h>
#include <float.h>

#define BB 16
#define CC 64
#define NN 2048
#define KNN 3
#define COUT 64
#define TM 128
#define QT 2  // queries per thread

// ---------------------------------------------------------------------------
// K1: transpose x[b][c][n] -> xt[b][n][c] (LDS tile) + per-point squared norms
// ---------------------------------------------------------------------------
__global__ __launch_bounds__(256) void k_prep(const float* __restrict__ x,
                                              float* __restrict__ xt,
                                              float* __restrict__ nrm) {
    __shared__ float t[64][65];
    const int b = blockIdx.x;
    const int n0 = blockIdx.y * 64;
    const int tid = threadIdx.x;
    const int ln = tid & 63, g = tid >> 6;
#pragma unroll
    for (int i = 0; i < 16; ++i) {
        const int c = g + 4 * i;
        t[c][ln] = x[((size_t)b * CC + c) * NN + n0 + ln];
    }
    __syncthreads();
#pragma unroll
    for (int i = 0; i < 16; ++i) {
        const int nl = g + 4 * i;
        xt[((size_t)b * NN + n0 + nl) * CC + ln] = t[ln][nl];
    }
    if (tid < 64) {
        float s = 0.f;
#pragma unroll
        for (int c = 0; c < 64; ++c) s = fmaf(t[c][tid], t[c][tid], s);
        nrm[(size_t)b * NN + n0 + tid] = s;
    }
}

// ---------------------------------------------------------------------------
// K2 (templated on SPLIT): top-3 over an m-range; 2 queries/thread.
// SPLIT=16 -> MRANGE=TM=128: one tile per block, 4 blocks/CU (4 waves/SIMD).
// dist = fmaf(-2, dot, sn + mn)  (same rounding as the passing round-1 code)
// ---------------------------------------------------------------------------
template <int SPL>
__global__ __launch_bounds__(256, 2) void k_top3(const float* __restrict__ xt,
                                                 const float* __restrict__ nrm,
                                                 float* __restrict__ pd,
                                                 int* __restrict__ pi) {
    constexpr int MRANGE = NN / SPL;
    __shared__ float mt[TM][64];  // 32 KB candidate tile
    __shared__ float mn[TM];
    const int b = blockIdx.x;
    const int tid = threadIdx.x;
    const int nA = blockIdx.y * (256 * QT) + tid;
    const int nB = nA + 256;
    const int s = blockIdx.z;

    float4 qA[16], qB[16];
    const float4* pA = (const float4*)(xt + ((size_t)b * NN + nA) * CC);
    const float4* pB = (const float4*)(xt + ((size_t)b * NN + nB) * CC);
#pragma unroll
    for (int i = 0; i < 16; ++i) qA[i] = pA[i];
#pragma unroll
    for (int i = 0; i < 16; ++i) qB[i] = pB[i];
    const float snA = nrm[(size_t)b * NN + nA];
    const float snB = nrm[(size_t)b * NN + nB];

    float dA0 = FLT_MAX, dA1 = FLT_MAX, dA2 = FLT_MAX;
    float dB0 = FLT_MAX, dB1 = FLT_MAX, dB2 = FLT_MAX;
    int iA0 = -1, iA1 = -1, iA2 = -1;
    int iB0 = -1, iB1 = -1, iB2 = -1;

    for (int t0 = 0; t0 < MRANGE; t0 += TM) {
        const int mb = s * MRANGE + t0;
        __syncthreads();
#pragma unroll
        for (int i = 0; i < 8; ++i) {  // stage 128x64 f32, coalesced
            const int t = tid + i * 256;
            const int row = t >> 4, c4 = t & 15;
            ((float4*)mt[row])[c4] =
                ((const float4*)(xt + ((size_t)b * NN + mb + row) * CC))[c4];
        }
        if (tid < TM) mn[tid] = nrm[(size_t)b * NN + mb + tid];
        __syncthreads();

        for (int mm = 0; mm < TM; ++mm) {
            const float4* mp = (const float4*)mt[mm];  // wave-uniform broadcast
            float4 cv[16];
#pragma unroll
            for (int i = 0; i < 16; ++i) cv[i] = mp[i];
            const float smn = mn[mm];
            float a0 = 0.f, a1 = 0.f, a2 = 0.f, a3 = 0.f;
            float b0 = 0.f, b1 = 0.f, b2 = 0.f, b3 = 0.f;
#pragma unroll
            for (int i = 0; i < 16; ++i) {
                const float4 c = cv[i];
                a0 = fmaf(qA[i].x, c.x, a0);
                a1 = fmaf(qA[i].y, c.y, a1);
                a2 = fmaf(qA[i].z, c.z, a2);
                a3 = fmaf(qA[i].w, c.w, a3);
                b0 = fmaf(qB[i].x, c.x, b0);
                b1 = fmaf(qB[i].y, c.y, b1);
                b2 = fmaf(qB[i].z, c.z, b2);
                b3 = fmaf(qB[i].w, c.w, b3);
            }
            const int m = mb + mm;
            const float dotA = (a0 + a1) + (a2 + a3);
            const float dA = fmaf(-2.f, dotA, snA + smn);
            if (dA < dA2) {  // rare after warm-up; strict < keeps tie-break
                const bool lt0 = dA < dA0, lt1 = dA < dA1;
                dA2 = lt1 ? dA1 : dA;  iA2 = lt1 ? iA1 : m;
                dA1 = lt0 ? dA0 : (lt1 ? dA : dA1);
                iA1 = lt0 ? iA0 : (lt1 ? m : iA1);
                dA0 = lt0 ? dA : dA0;  iA0 = lt0 ? m : iA0;
            }
            const float dotB = (b0 + b1) + (b2 + b3);
            const float dB = fmaf(-2.f, dotB, snB + smn);
            if (dB < dB2) {
                const bool lt0 = dB < dB0, lt1 = dB < dB1;
                dB2 = lt1 ? dB1 : dB;  iB2 = lt1 ? iB1 : m;
                dB1 = lt0 ? dB0 : (lt1 ? dB : dB1);
                iB1 = lt0 ? iB0 : (lt1 ? m : iB1);
                dB0 = lt0 ? dB : dB0;  iB0 = lt0 ? m : iB0;
            }
        }
    }
    const size_t oA = (((size_t)b * SPL + s) * NN + nA) * 3;
    pd[oA] = dA0; pd[oA + 1] = dA1; pd[oA + 2] = dA2;
    pi[oA] = iA0; pi[oA + 1] = iA1; pi[oA + 2] = iA2;
    const size_t oB = (((size_t)b * SPL + s) * NN + nB) * 3;
    pd[oB] = dB0; pd[oB + 1] = dB1; pd[oB + 2] = dB2;
    pi[oB] = iB0; pi[oB + 1] = iB1; pi[oB + 2] = iB2;
}

// ---------------------------------------------------------------------------
// K3 (templated): merge SPL sorted top-3 lists, (d, idx) lexicographic.
// Static indexing only (fully unrolled) so arrays stay in registers.
// ---------------------------------------------------------------------------
template <int SPL>
__global__ __launch_bounds__(256) void k_merge(const float* __restrict__ pd,
                                               const int* __restrict__ pi,
                                               int* __restrict__ fi) {
    const int t = blockIdx.x * 256 + threadIdx.x;
    if (t >= BB * NN) return;
    const int b = t / NN, n = t % NN;
    float dv[3 * SPL]; int iv[3 * SPL];
#pragma unroll
    for (int s = 0; s < SPL; ++s) {
        const size_t o = (((size_t)b * SPL + s) * NN + n) * 3;
#pragma unroll
        for (int r = 0; r < 3; ++r) {
            dv[s * 3 + r] = pd[o + r];
            iv[s * 3 + r] = pi[o + r];
        }
    }
    float bd = -FLT_MAX; int bi = -1;
#pragma unroll
    for (int r = 0; r < 3; ++r) {
        float cd = FLT_MAX; int ci = 0x7fffffff;
#pragma unroll
        for (int j = 0; j < 3 * SPL; ++j) {
            const bool gt_prev = (dv[j] > bd) || (dv[j] == bd && iv[j] > bi);
            const bool lt_cur = (dv[j] < cd) || (dv[j] == cd && iv[j] < ci);
            if (gt_prev && lt_cur) { cd = dv[j]; ci = iv[j]; }
        }
        fi[(size_t)t * 3 + r] = ci;
        bd = cd; bi = ci;
    }
}

// ---------------------------------------------------------------------------
// K4: gather neighbors + 1x3/stride-3 conv + bias + relu
// ---------------------------------------------------------------------------
__global__ __launch_bounds__(256) void k_conv(const float* __restrict__ xt,
                                              const int* __restrict__ fi,
                                              const float* __restrict__ W,
                                              const float* __restrict__ bias,
                                              float* __restrict__ out) {
    __shared__ float Wl[KNN][CC][COUT];  // 48 KB
    const int b = blockIdx.x, n0 = blockIdx.y * 64;
    const int tid = threadIdx.x;
    const int nl = tid & 63, g = tid >> 6;
    for (int t = tid; t < COUT * CC * KNN; t += 256) {
        const int co = t / (CC * KNN);
        const int rem = t % (CC * KNN);
        const int c = rem / KNN, k = rem % KNN;
        Wl[k][c][co] = W[t];
    }
    __syncthreads();

    const int cobase = g * 16;
    float4 acc[4];
#pragma unroll
    for (int j = 0; j < 4; ++j) acc[j] = *(const float4*)&bias[cobase + j * 4];

    const size_t fbase = ((size_t)b * NN + n0 + nl) * 3;
#pragma unroll
    for (int k = 0; k < KNN; ++k) {
        const int src = fi[fbase + k];
        const float4* vrow = (const float4*)(xt + ((size_t)b * NN + src) * CC);
#pragma unroll
        for (int c4 = 0; c4 < 16; ++c4) {
            const float4 p = vrow[c4];
#pragma unroll
            for (int cp = 0; cp < 4; ++cp) {
                const float pv = (&p.x)[cp];
                const float4* wr = (const float4*)&Wl[k][c4 * 4 + cp][cobase];
#pragma unroll
                for (int j = 0; j < 4; ++j) {
                    const float4 w = wr[j];
                    acc[j].x = fmaf(pv, w.x, acc[j].x);
                    acc[j].y = fmaf(pv, w.y, acc[j].y);
                    acc[j].z = fmaf(pv, w.z, acc[j].z);
                    acc[j].w = fmaf(pv, w.w, acc[j].w);
                }
            }
        }
    }
#pragma unroll
    for (int j = 0; j < 4; ++j) {
#pragma unroll
        for (int cp = 0; cp < 4; ++cp) {
            const int co = cobase + j * 4 + cp;
            const float v = fmaxf((&acc[j].x)[cp], 0.f);
            out[((size_t)b * COUT + co) * NN + n0 + nl] = v;
        }
    }
}

extern "C" void kernel_launch(void* const* d_in, const int* in_sizes, int n_in,
                              void* d_out, int out_size, void* d_ws, size_t ws_size,
                              hipStream_t stream) {
    const float* x = (const float*)d_in[0];
    const float* W = (const float*)d_in[1];
    const float* bias = (const float*)d_in[2];
    float* out = (float*)d_out;

    char* ws = (char*)d_ws;
    float* xt = (float*)(ws);                 // 8,388,608 B
    float* nrm = (float*)(ws + 8388608);      //   131,072 B
    char* rest = ws + 8519680;

    k_prep<<<dim3(BB, NN / 64), 256, 0, stream>>>(x, xt, nrm);

    // SPLIT=16 needs 8,519,680 + 2*6,291,456 + 393,216 = 21,495,808 B of ws.
    const size_t need16 = 8519680ull + 2ull * 6291456ull + 393216ull;
    if (ws_size >= need16) {
        constexpr int SPL = 16;
        const size_t psz = (size_t)BB * SPL * NN * 3 * 4;  // 6,291,456
        float* pd = (float*)rest;
        int* pi = (int*)(rest + psz);
        int* fi = (int*)(rest + 2 * psz);
        k_top3<SPL><<<dim3(BB, NN / (256 * QT), SPL), 256, 0, stream>>>(xt, nrm, pd, pi);
        k_merge<SPL><<<(BB * NN + 255) / 256, 256, 0, stream>>>(pd, pi, fi);
        k_conv<<<dim3(BB, NN / 64), 256, 0, stream>>>(xt, fi, W, bias, out);
    } else {
        constexpr int SPL = 8;
        const size_t psz = (size_t)BB * SPL * NN * 3 * 4;  // 3,145,728
        float* pd = (float*)rest;
        int* pi = (int*)(rest + psz);
        int* fi = (int*)(rest + 2 * psz);
        k_top3<SPL><<<dim3(BB, NN / (256 * QT), SPL), 256, 0, stream>>>(xt, nrm, pd, pi);
        k_merge<SPL><<<(BB * NN + 255) / 256, 256, 0, stream>>>(pd, pi, fi);
        k_conv<<<dim3(BB, NN / 64), 256, 0, stream>>>(xt, fi, W, bias, out);
    }
}

// Round 4
// 190.417 us; speedup vs baseline: 1.1207x; 1.1207x over previous
//
#include <hip/hip_runtime.h>
#include <float.h>

#define BB 16
#define CC 64
#define NN 2048
#define KNN 3
#define COUT 64
#define SPLIT 8

// ---------------------------------------------------------------------------
// K1: transpose x[b][c][n] -> xt[b][n][c] (LDS tile) + per-point squared norms
// ---------------------------------------------------------------------------
__global__ __launch_bounds__(256) void k_prep(const float* __restrict__ x,
                                              float* __restrict__ xt,
                                              float* __restrict__ nrm) {
    __shared__ float t[64][65];
    const int b = blockIdx.x;
    const int n0 = blockIdx.y * 64;
    const int tid = threadIdx.x;
    const int ln = tid & 63, g = tid >> 6;
#pragma unroll
    for (int i = 0; i < 16; ++i) {
        const int c = g + 4 * i;
        t[c][ln] = x[((size_t)b * CC + c) * NN + n0 + ln];
    }
    __syncthreads();
#pragma unroll
    for (int i = 0; i < 16; ++i) {
        const int nl = g + 4 * i;
        xt[((size_t)b * NN + n0 + nl) * CC + ln] = t[ln][nl];
    }
    if (tid < 64) {
        float s = 0.f;
#pragma unroll
        for (int c = 0; c < 64; ++c) s = fmaf(t[c][tid], t[c][tid], s);
        nrm[(size_t)b * NN + n0 + tid] = s;
    }
}

// ---------------------------------------------------------------------------
// K2: top-3 over an m-range. One query per thread (q row in 64 VGPRs).
// Candidate row address is wave-uniform (blockIdx + loop counter only) ->
// compiler emits scalar s_load into SGPRs; FMA = v_fma(vgpr, sgpr, vgpr).
// Inner loop: NO LDS, NO per-lane VMEM -> pure VALU issue.
// dist = fmaf(-2, dot, sn + mn), 4-acc pattern identical to passing rounds.
// ---------------------------------------------------------------------------
template <int SPL>
__global__ __launch_bounds__(256) void k_top3(const float* __restrict__ xt,
                                              const float* __restrict__ nrm,
                                              float* __restrict__ pd,
                                              int* __restrict__ pi) {
    constexpr int MRANGE = NN / SPL;
    const int b = blockIdx.x;
    const int n = blockIdx.y * 256 + threadIdx.x;
    const int s = blockIdx.z;

    float4 q[16];
    const float4* qp = (const float4*)(xt + ((size_t)b * NN + n) * CC);
#pragma unroll
    for (int i = 0; i < 16; ++i) q[i] = qp[i];
    const float sn = nrm[(size_t)b * NN + n];

    float d0 = FLT_MAX, d1 = FLT_MAX, d2 = FLT_MAX;
    int i0 = -1, i1 = -1, i2 = -1;

    const int mb = s * MRANGE;
    const float* xb = xt + (size_t)b * NN * CC;   // uniform base
    const float* nb = nrm + (size_t)b * NN;       // uniform base

    for (int mm = 0; mm < MRANGE; ++mm) {
        const int m = mb + mm;
        const float smn = nb[m];                        // uniform scalar load
        const float4* crow = (const float4*)(xb + (size_t)m * CC);  // uniform
        float a0 = 0.f, a1 = 0.f, a2 = 0.f, a3 = 0.f;
#pragma unroll
        for (int i = 0; i < 16; ++i) {
            const float4 c = crow[i];                   // uniform -> SGPRs
            a0 = fmaf(q[i].x, c.x, a0);
            a1 = fmaf(q[i].y, c.y, a1);
            a2 = fmaf(q[i].z, c.z, a2);
            a3 = fmaf(q[i].w, c.w, a3);
        }
        const float dot = (a0 + a1) + (a2 + a3);
        const float d = fmaf(-2.f, dot, sn + smn);
        // branchless sorted-insert; strict < keeps lower-index-first ties
        const bool lt0 = d < d0, lt1 = d < d1, lt2 = d < d2;
        d2 = lt1 ? d1 : (lt2 ? d : d2);
        i2 = lt1 ? i1 : (lt2 ? m : i2);
        d1 = lt0 ? d0 : (lt1 ? d : d1);
        i1 = lt0 ? i0 : (lt1 ? m : i1);
        d0 = lt0 ? d : d0;
        i0 = lt0 ? m : i0;
    }
    const size_t o = (((size_t)b * SPL + s) * NN + n) * 3;
    pd[o] = d0; pd[o + 1] = d1; pd[o + 2] = d2;
    pi[o] = i0; pi[o + 1] = i1; pi[o + 2] = i2;
}

// ---------------------------------------------------------------------------
// K3: merge SPL sorted top-3 lists, (d, idx) lexicographic. Fully unrolled,
// static indexing only so arrays stay in registers.
// ---------------------------------------------------------------------------
template <int SPL>
__global__ __launch_bounds__(256) void k_merge(const float* __restrict__ pd,
                                               const int* __restrict__ pi,
                                               int* __restrict__ fi) {
    const int t = blockIdx.x * 256 + threadIdx.x;
    if (t >= BB * NN) return;
    const int b = t / NN, n = t % NN;
    float dv[3 * SPL]; int iv[3 * SPL];
#pragma unroll
    for (int s = 0; s < SPL; ++s) {
        const size_t o = (((size_t)b * SPL + s) * NN + n) * 3;
#pragma unroll
        for (int r = 0; r < 3; ++r) {
            dv[s * 3 + r] = pd[o + r];
            iv[s * 3 + r] = pi[o + r];
        }
    }
    float bd = -FLT_MAX; int bi = -1;
#pragma unroll
    for (int r = 0; r < 3; ++r) {
        float cd = FLT_MAX; int ci = 0x7fffffff;
#pragma unroll
        for (int j = 0; j < 3 * SPL; ++j) {
            const bool gt_prev = (dv[j] > bd) || (dv[j] == bd && iv[j] > bi);
            const bool lt_cur = (dv[j] < cd) || (dv[j] == cd && iv[j] < ci);
            if (gt_prev && lt_cur) { cd = dv[j]; ci = iv[j]; }
        }
        fi[(size_t)t * 3 + r] = ci;
        bd = cd; bi = ci;
    }
}

// ---------------------------------------------------------------------------
// K4: gather neighbors + 1x3/stride-3 conv + bias + relu
// ---------------------------------------------------------------------------
__global__ __launch_bounds__(256) void k_conv(const float* __restrict__ xt,
                                              const int* __restrict__ fi,
                                              const float* __restrict__ W,
                                              const float* __restrict__ bias,
                                              float* __restrict__ out) {
    __shared__ float Wl[KNN][CC][COUT];  // 48 KB
    const int b = blockIdx.x, n0 = blockIdx.y * 64;
    const int tid = threadIdx.x;
    const int nl = tid & 63, g = tid >> 6;
    for (int t = tid; t < COUT * CC * KNN; t += 256) {
        const int co = t / (CC * KNN);
        const int rem = t % (CC * KNN);
        const int c = rem / KNN, k = rem % KNN;
        Wl[k][c][co] = W[t];
    }
    __syncthreads();

    const int cobase = g * 16;
    float4 acc[4];
#pragma unroll
    for (int j = 0; j < 4; ++j) acc[j] = *(const float4*)&bias[cobase + j * 4];

    const size_t fbase = ((size_t)b * NN + n0 + nl) * 3;
#pragma unroll
    for (int k = 0; k < KNN; ++k) {
        const int src = fi[fbase + k];
        const float4* vrow = (const float4*)(xt + ((size_t)b * NN + src) * CC);
#pragma unroll
        for (int c4 = 0; c4 < 16; ++c4) {
            const float4 p = vrow[c4];
#pragma unroll
            for (int cp = 0; cp < 4; ++cp) {
                const float pv = (&p.x)[cp];
                const float4* wr = (const float4*)&Wl[k][c4 * 4 + cp][cobase];
#pragma unroll
                for (int j = 0; j < 4; ++j) {
                    const float4 w = wr[j];
                    acc[j].x = fmaf(pv, w.x, acc[j].x);
                    acc[j].y = fmaf(pv, w.y, acc[j].y);
                    acc[j].z = fmaf(pv, w.z, acc[j].z);
                    acc[j].w = fmaf(pv, w.w, acc[j].w);
                }
            }
        }
    }
#pragma unroll
    for (int j = 0; j < 4; ++j) {
#pragma unroll
        for (int cp = 0; cp < 4; ++cp) {
            const int co = cobase + j * 4 + cp;
            const float v = fmaxf((&acc[j].x)[cp], 0.f);
            out[((size_t)b * COUT + co) * NN + n0 + nl] = v;
        }
    }
}

extern "C" void kernel_launch(void* const* d_in, const int* in_sizes, int n_in,
                              void* d_out, int out_size, void* d_ws, size_t ws_size,
                              hipStream_t stream) {
    const float* x = (const float*)d_in[0];
    const float* W = (const float*)d_in[1];
    const float* bias = (const float*)d_in[2];
    float* out = (float*)d_out;

    char* ws = (char*)d_ws;
    float* xt = (float*)(ws);                   //  8,388,608 B
    float* nrm = (float*)(ws + 8388608);        //    131,072 B
    float* pd = (float*)(ws + 8519680);         //  3,145,728 B
    int* pi = (int*)(ws + 11665408);            //  3,145,728 B
    int* fi = (int*)(ws + 14811136);            //    393,216 B (total ~14.5 MB)

    k_prep<<<dim3(BB, NN / 64), 256, 0, stream>>>(x, xt, nrm);
    k_top3<SPLIT><<<dim3(BB, NN / 256, SPLIT), 256, 0, stream>>>(xt, nrm, pd, pi);
    k_merge<SPLIT><<<(BB * NN + 255) / 256, 256, 0, stream>>>(pd, pi, fi);
    k_conv<<<dim3(BB, NN / 64), 256, 0, stream>>>(xt, fi, W, bias, out);
}

// Round 5
// 92.731 us; speedup vs baseline: 2.3014x; 2.0534x over previous
//
#include <hip/hip_runtime.h>
#include <float.h>

#define BB 16
#define CC 64
#define NN 2048
#define KNN 3
#define COUT 64
#define SPL 4   // candidate-range splits

typedef _Float16 half8 __attribute__((ext_vector_type(8)));
typedef float f32x16 __attribute__((ext_vector_type(16)));

// ---------------------------------------------------------------------------
// K1: from x[b][c][n] produce:
//   xt[b][n][c]  (f32, for the conv gather)
//   xe[b][ct][kblk][lane] (16B fp16x8 MFMA fragments of ext=[hi|lo], K=128)
//   anc[b][ct][lane] (packed fp16 pair (-nc/2 hi, -nc/2 lo) for lanes<32)
// Fragment convention (m97-verified family): row m = lane&31,
// k = kblk*16 + 8*(lane>>5) + j, j=0..7 contiguous.
// ---------------------------------------------------------------------------
__global__ __launch_bounds__(256) void k_prep(const float* __restrict__ x,
                                              float* __restrict__ xt,
                                              uint4* __restrict__ xe,
                                              unsigned* __restrict__ anc) {
    __shared__ float t[64][65];
    __shared__ float nsh[64];
    const int b = blockIdx.x;
    const int n0 = blockIdx.y * 64;
    const int tid = threadIdx.x;
    const int ln = tid & 63, g = tid >> 6;
#pragma unroll
    for (int i = 0; i < 16; ++i) {
        const int c = g + 4 * i;
        t[c][ln] = x[((size_t)b * CC + c) * NN + n0 + ln];
    }
    __syncthreads();
#pragma unroll
    for (int i = 0; i < 16; ++i) {
        const int nl = g + 4 * i;
        xt[((size_t)b * NN + n0 + nl) * CC + ln] = t[ln][nl];
    }
    if (tid < 64) {
        float s = 0.f;
#pragma unroll
        for (int c = 0; c < 64; ++c) s = fmaf(t[c][tid], t[c][tid], s);
        nsh[tid] = s;
    }
    // fragment packing: 1024 16B chunks per 64-point group
#pragma unroll
    for (int i = 0; i < 4; ++i) {
        const int cid = tid + 256 * i;
        const int lane = cid & 63;
        const int kblk = (cid >> 6) & 7;
        const int ctl = cid >> 9;               // 0..1
        const int m = ctl * 32 + (lane & 31);   // local point
        const int khalf = (lane >> 5) * 8;
        union { uint4 v; _Float16 h[8]; } pk;
#pragma unroll
        for (int j = 0; j < 8; ++j) {
            const int kg = kblk * 16 + khalf + j;
            const int ch = kg & 63;
            const float f = t[ch][m];
            const _Float16 hi = (_Float16)f;
            pk.h[j] = (kg < 64) ? hi : (_Float16)(f - (float)hi);
        }
        const int ct = (n0 >> 5) + ctl;
        xe[((size_t)(b * 64 + ct) * 8 + kblk) * 64 + lane] = pk.v;
    }
    __syncthreads();
    if (tid < 128) {
        const int ctl = tid >> 6, l = tid & 63;
        const int ct = (n0 >> 5) + ctl;
        unsigned v = 0;
        if (l < 32) {
            const float h = -0.5f * nsh[ctl * 32 + l];
            const _Float16 a0 = (_Float16)h;
            const _Float16 a1 = (_Float16)(h - (float)a0);
            union { unsigned u; _Float16 hh[2]; } cu;
            cu.hh[0] = a0; cu.hh[1] = a1;
            v = cu.u;
        }
        anc[(size_t)(b * 64 + ct) * 64 + l] = v;
    }
}

// ---------------------------------------------------------------------------
// K2: MFMA top-3. Wave = 32 queries (B operand, resident); loops 16 candidate
// tiles (A operand). acc[m][n] = dot(cand_m, query_n) - nc_m/2 via
// 2 passes of K=128 fp16-split + 1 norm-fold MFMA. Rank by LARGEST acc
// (key = -2*acc = nc - 2*dot); ascending-index iteration + strict > keeps
// lax.top_k's lower-index tie-break. Halves merged via shfl_xor(32).
// ---------------------------------------------------------------------------
__global__ __launch_bounds__(256, 4) void k_top3(const half8* __restrict__ xe,
                                                 const unsigned* __restrict__ anc,
                                                 float* __restrict__ pd,
                                                 int* __restrict__ pi) {
    const int tid = threadIdx.x;
    const int lane = tid & 63;
    const int qg = blockIdx.x * 4 + (tid >> 6);
    const int s = blockIdx.y;
    const int b = blockIdx.z;

    // resident query fragments (8 kblks x 16B)
    half8 bq[8];
#pragma unroll
    for (int kb = 0; kb < 8; ++kb)
        bq[kb] = xe[((size_t)(b * 64 + qg) * 8 + kb) * 64 + lane];

    // constant B fragment for the norm-fold k-block: B[n][k0]=B[n][k1]=1
    half8 bnc = {};
    if (lane < 32) { bnc[0] = (_Float16)1.0f; bnc[1] = (_Float16)1.0f; }

    float k0 = -FLT_MAX, k1 = -FLT_MAX, k2 = -FLT_MAX;
    int i0 = -1, i1 = -1, i2 = -1;
    const int hi4 = (lane >> 5) * 4;

    const int ct0 = s * (NN / 32 / SPL);  // 16 tiles per wave
    for (int t = 0; t < NN / 32 / SPL; ++t) {
        const int ct = ct0 + t;
        half8 af[8];
#pragma unroll
        for (int kb = 0; kb < 8; ++kb)
            af[kb] = xe[((size_t)(b * 64 + ct) * 8 + kb) * 64 + lane];
        half8 av = {};
        {
            union { unsigned u; _Float16 hh[2]; } cu;
            cu.u = anc[(size_t)(b * 64 + ct) * 64 + lane];
            av[0] = cu.hh[0]; av[1] = cu.hh[1];
        }
        f32x16 acc = {};
#pragma unroll
        for (int kb = 0; kb < 8; ++kb)   // hihi + lolo
            acc = __builtin_amdgcn_mfma_f32_32x32x16_f16(af[kb], bq[kb], acc, 0, 0, 0);
#pragma unroll
        for (int kb = 0; kb < 8; ++kb)   // hilo + lohi
            acc = __builtin_amdgcn_mfma_f32_32x32x16_f16(af[kb], bq[(kb + 4) & 7], acc, 0, 0, 0);
        acc = __builtin_amdgcn_mfma_f32_32x32x16_f16(av, bnc, acc, 0, 0, 0);

        const int mbase = ct * 32 + hi4;
#pragma unroll
        for (int j = 0; j < 16; ++j) {
            const float a = acc[j];
            if (__any(a > k2)) {
                const int m = mbase + (j & 3) + 8 * (j >> 2);
                const bool g0 = a > k0, g1 = a > k1, g2 = a > k2;
                k2 = g1 ? k1 : (g2 ? a : k2); i2 = g1 ? i1 : (g2 ? m : i2);
                k1 = g0 ? k0 : (g1 ? a : k1); i1 = g0 ? i0 : (g1 ? m : i1);
                k0 = g0 ? a : k0;             i0 = g0 ? m : i0;
            }
        }
    }

    // merge the two lane-halves (disjoint candidate rows) lexicographically
    const float ok[3] = {__shfl_xor(k0, 32), __shfl_xor(k1, 32), __shfl_xor(k2, 32)};
    const int oi[3] = {__shfl_xor(i0, 32), __shfl_xor(i1, 32), __shfl_xor(i2, 32)};
#pragma unroll
    for (int r = 0; r < 3; ++r) {
        const float ck = ok[r]; const int ci = oi[r];
        const bool b0 = (ck > k0) || (ck == k0 && ci < i0);
        const bool b1 = (ck > k1) || (ck == k1 && ci < i1);
        const bool b2 = (ck > k2) || (ck == k2 && ci < i2);
        k2 = b1 ? k1 : (b2 ? ck : k2); i2 = b1 ? i1 : (b2 ? ci : i2);
        k1 = b0 ? k0 : (b1 ? ck : k1); i1 = b0 ? i0 : (b1 ? ci : i1);
        k0 = b0 ? ck : k0;             i0 = b0 ? ci : i0;
    }
    if (lane < 32) {
        const int q = qg * 32 + lane;
        const size_t o = (((size_t)b * SPL + s) * NN + q) * 3;
        pd[o] = -2.0f * k0; pd[o + 1] = -2.0f * k1; pd[o + 2] = -2.0f * k2;
        pi[o] = i0; pi[o + 1] = i1; pi[o + 2] = i2;
    }
}

// ---------------------------------------------------------------------------
// K3: merge SPL sorted top-3 lists, (key, idx) lexicographic; fully unrolled.
// ---------------------------------------------------------------------------
__global__ __launch_bounds__(256) void k_merge(const float* __restrict__ pd,
                                               const int* __restrict__ pi,
                                               int* __restrict__ fi) {
    const int t = blockIdx.x * 256 + threadIdx.x;
    if (t >= BB * NN) return;
    const int b = t / NN, n = t % NN;
    float dv[3 * SPL]; int iv[3 * SPL];
#pragma unroll
    for (int s = 0; s < SPL; ++s) {
        const size_t o = (((size_t)b * SPL + s) * NN + n) * 3;
#pragma unroll
        for (int r = 0; r < 3; ++r) {
            dv[s * 3 + r] = pd[o + r];
            iv[s * 3 + r] = pi[o + r];
        }
    }
    float bd = -FLT_MAX; int bi = -1;
#pragma unroll
    for (int r = 0; r < 3; ++r) {
        float cd = FLT_MAX; int ci = 0x7fffffff;
#pragma unroll
        for (int j = 0; j < 3 * SPL; ++j) {
            const bool gt_prev = (dv[j] > bd) || (dv[j] == bd && iv[j] > bi);
            const bool lt_cur = (dv[j] < cd) || (dv[j] == cd && iv[j] < ci);
            if (gt_prev && lt_cur) { cd = dv[j]; ci = iv[j]; }
        }
        fi[(size_t)t * 3 + r] = ci;
        bd = cd; bi = ci;
    }
}

// ---------------------------------------------------------------------------
// K4: gather neighbors + 1x3/stride-3 conv + bias + relu
// ---------------------------------------------------------------------------
__global__ __launch_bounds__(256) void k_conv(const float* __restrict__ xt,
                                              const int* __restrict__ fi,
                                              const float* __restrict__ W,
                                              const float* __restrict__ bias,
                                              float* __restrict__ out) {
    __shared__ float Wl[KNN][CC][COUT];  // 48 KB
    const int b = blockIdx.x, n0 = blockIdx.y * 64;
    const int tid = threadIdx.x;
    const int nl = tid & 63, g = tid >> 6;
    for (int t = tid; t < COUT * CC * KNN; t += 256) {
        const int co = t / (CC * KNN);
        const int rem = t % (CC * KNN);
        const int c = rem / KNN, k = rem % KNN;
        Wl[k][c][co] = W[t];
    }
    __syncthreads();

    const int cobase = g * 16;
    float4 acc[4];
#pragma unroll
    for (int j = 0; j < 4; ++j) acc[j] = *(const float4*)&bias[cobase + j * 4];

    const size_t fbase = ((size_t)b * NN + n0 + nl) * 3;
#pragma unroll
    for (int k = 0; k < KNN; ++k) {
        const int src = fi[fbase + k];
        const float4* vrow = (const float4*)(xt + ((size_t)b * NN + src) * CC);
#pragma unroll
        for (int c4 = 0; c4 < 16; ++c4) {
            const float4 p = vrow[c4];
#pragma unroll
            for (int cp = 0; cp < 4; ++cp) {
                const float pv = (&p.x)[cp];
                const float4* wr = (const float4*)&Wl[k][c4 * 4 + cp][cobase];
#pragma unroll
                for (int j = 0; j < 4; ++j) {
                    const float4 w = wr[j];
                    acc[j].x = fmaf(pv, w.x, acc[j].x);
                    acc[j].y = fmaf(pv, w.y, acc[j].y);
                    acc[j].z = fmaf(pv, w.z, acc[j].z);
                    acc[j].w = fmaf(pv, w.w, acc[j].w);
                }
            }
        }
    }
#pragma unroll
    for (int j = 0; j < 4; ++j) {
#pragma unroll
        for (int cp = 0; cp < 4; ++cp) {
            const int co = cobase + j * 4 + cp;
            const float v = fmaxf((&acc[j].x)[cp], 0.f);
            out[((size_t)b * COUT + co) * NN + n0 + nl] = v;
        }
    }
}

extern "C" void kernel_launch(void* const* d_in, const int* in_sizes, int n_in,
                              void* d_out, int out_size, void* d_ws, size_t ws_size,
                              hipStream_t stream) {
    const float* x = (const float*)d_in[0];
    const float* W = (const float*)d_in[1];
    const float* bias = (const float*)d_in[2];
    float* out = (float*)d_out;

    char* ws = (char*)d_ws;
    float* xt = (float*)(ws);                       //  8,388,608 B
    uint4* xe = (uint4*)(ws + 8388608);             //  8,388,608 B
    unsigned* anc = (unsigned*)(ws + 16777216);     //    262,144 B
    float* pd = (float*)(ws + 17039360);            //  1,572,864 B
    int* pi = (int*)(ws + 18612224);                //  1,572,864 B
    int* fi = (int*)(ws + 20185088);                //    393,216 B (end 20.6 MB)

    k_prep<<<dim3(BB, NN / 64), 256, 0, stream>>>(x, xt, xe, anc);
    k_top3<<<dim3(16, SPL, BB), 256, 0, stream>>>((const half8*)xe, anc, pd, pi);
    k_merge<<<(BB * NN + 255) / 256, 256, 0, stream>>>(pd, pi, fi);
    k_conv<<<dim3(BB, NN / 64), 256, 0, stream>>>(xt, fi, W, bias, out);
}

// Round 6
// 78.108 us; speedup vs baseline: 2.7322x; 1.1872x over previous
//
#include <hip/hip_runtime.h>
#include <float.h>

#define BB 16
#define CC 64
#define NN 2048
#define KNN 3
#define COUT 64
#define SPL 4   // candidate-range splits

typedef _Float16 half8 __attribute__((ext_vector_type(8)));
typedef float f32x16 __attribute__((ext_vector_type(16)));

// ---------------------------------------------------------------------------
// K1: from x[b][c][n] produce:
//   xe[b][ct][kblk][lane] (16B fp16x8 MFMA fragments of ext=[hi|lo], K=128)
//   anc[b][ct][lane] (packed fp16 pair (-nc/2 hi, -nc/2 lo) for lanes<32)
// Fragment convention: row m = lane&31, k = kblk*16 + 8*(lane>>5) + j.
// kblk 0..3 = hi(x[c]) (c = k), kblk 4..7 = lo residual (c = k-64).
// ---------------------------------------------------------------------------
__global__ __launch_bounds__(256) void k_prep(const float* __restrict__ x,
                                              uint4* __restrict__ xe,
                                              unsigned* __restrict__ anc) {
    __shared__ float t[64][65];
    __shared__ float nsh[64];
    const int b = blockIdx.x;
    const int n0 = blockIdx.y * 64;
    const int tid = threadIdx.x;
    const int ln = tid & 63, g = tid >> 6;
#pragma unroll
    for (int i = 0; i < 16; ++i) {
        const int c = g + 4 * i;
        t[c][ln] = x[((size_t)b * CC + c) * NN + n0 + ln];
    }
    __syncthreads();
    if (tid < 64) {
        float s = 0.f;
#pragma unroll
        for (int c = 0; c < 64; ++c) s = fmaf(t[c][tid], t[c][tid], s);
        nsh[tid] = s;
    }
    // fragment packing: 1024 16B chunks per 64-point group
#pragma unroll
    for (int i = 0; i < 4; ++i) {
        const int cid = tid + 256 * i;
        const int lane = cid & 63;
        const int kblk = (cid >> 6) & 7;
        const int ctl = cid >> 9;               // 0..1
        const int m = ctl * 32 + (lane & 31);   // local point
        const int khalf = (lane >> 5) * 8;
        union { uint4 v; _Float16 h[8]; } pk;
#pragma unroll
        for (int j = 0; j < 8; ++j) {
            const int kg = kblk * 16 + khalf + j;
            const int ch = kg & 63;
            const float f = t[ch][m];
            const _Float16 hi = (_Float16)f;
            pk.h[j] = (kg < 64) ? hi : (_Float16)(f - (float)hi);
        }
        const int ct = (n0 >> 5) + ctl;
        xe[((size_t)(b * 64 + ct) * 8 + kblk) * 64 + lane] = pk.v;
    }
    __syncthreads();
    if (tid < 128) {
        const int ctl = tid >> 6, l = tid & 63;
        const int ct = (n0 >> 5) + ctl;
        unsigned v = 0;
        if (l < 32) {
            const float h = -0.5f * nsh[ctl * 32 + l];
            const _Float16 a0 = (_Float16)h;
            const _Float16 a1 = (_Float16)(h - (float)a0);
            union { unsigned u; _Float16 hh[2]; } cu;
            cu.hh[0] = a0; cu.hh[1] = a1;
            v = cu.u;
        }
        anc[(size_t)(b * 64 + ct) * 64 + l] = v;
    }
}

// ---------------------------------------------------------------------------
// K1b: pack W into fp16 B-fragments. Wf[((kk*2+ct2)*4+kb)*64 + lane]:
// co = ct2*32 + (lane&31), c = kb*16 + 8*(lane>>5) + j, value = fp16(W[co][c][kk])
// ---------------------------------------------------------------------------
__global__ __launch_bounds__(256) void k_wprep(const float* __restrict__ W,
                                               uint4* __restrict__ Wf) {
    const int tid = threadIdx.x;
#pragma unroll
    for (int i = 0; i < 6; ++i) {
        const int id = tid + 256 * i;  // == ((kk*2+ct2)*4+kb)*64 + l
        const int l = id & 63;
        const int kb = (id >> 6) & 3;
        const int ct2 = (id >> 8) & 1;
        const int kk = id >> 9;
        const int co = ct2 * 32 + (l & 31);
        union { uint4 v; _Float16 h[8]; } pk;
#pragma unroll
        for (int j = 0; j < 8; ++j) {
            const int c = kb * 16 + 8 * (l >> 5) + j;
            pk.h[j] = (_Float16)W[(co * CC + c) * KNN + kk];
        }
        Wf[id] = pk.v;
    }
}

// ---------------------------------------------------------------------------
// K2: MFMA top-3. Wave = 32 queries (B operand, resident); loops 16 candidate
// tiles (A operand). acc[m][n] = dot(cand_m, query_n) - nc_m/2 via
// 2 passes of K=128 fp16-split + 1 norm-fold MFMA. Rank by LARGEST acc.
// ---------------------------------------------------------------------------
__global__ __launch_bounds__(256, 4) void k_top3(const half8* __restrict__ xe,
                                                 const unsigned* __restrict__ anc,
                                                 float* __restrict__ pd,
                                                 int* __restrict__ pi) {
    const int tid = threadIdx.x;
    const int lane = tid & 63;
    const int qg = blockIdx.x * 4 + (tid >> 6);
    const int s = blockIdx.y;
    const int b = blockIdx.z;

    half8 bq[8];
#pragma unroll
    for (int kb = 0; kb < 8; ++kb)
        bq[kb] = xe[((size_t)(b * 64 + qg) * 8 + kb) * 64 + lane];

    half8 bnc = {};
    if (lane < 32) { bnc[0] = (_Float16)1.0f; bnc[1] = (_Float16)1.0f; }

    float k0 = -FLT_MAX, k1 = -FLT_MAX, k2 = -FLT_MAX;
    int i0 = -1, i1 = -1, i2 = -1;
    const int hi4 = (lane >> 5) * 4;

    const int ct0 = s * (NN / 32 / SPL);
    for (int t = 0; t < NN / 32 / SPL; ++t) {
        const int ct = ct0 + t;
        half8 af[8];
#pragma unroll
        for (int kb = 0; kb < 8; ++kb)
            af[kb] = xe[((size_t)(b * 64 + ct) * 8 + kb) * 64 + lane];
        half8 av = {};
        {
            union { unsigned u; _Float16 hh[2]; } cu;
            cu.u = anc[(size_t)(b * 64 + ct) * 64 + lane];
            av[0] = cu.hh[0]; av[1] = cu.hh[1];
        }
        f32x16 acc = {};
#pragma unroll
        for (int kb = 0; kb < 8; ++kb)   // hihi + lolo
            acc = __builtin_amdgcn_mfma_f32_32x32x16_f16(af[kb], bq[kb], acc, 0, 0, 0);
#pragma unroll
        for (int kb = 0; kb < 8; ++kb)   // hilo + lohi
            acc = __builtin_amdgcn_mfma_f32_32x32x16_f16(af[kb], bq[(kb + 4) & 7], acc, 0, 0, 0);
        acc = __builtin_amdgcn_mfma_f32_32x32x16_f16(av, bnc, acc, 0, 0, 0);

        const int mbase = ct * 32 + hi4;
#pragma unroll
        for (int j = 0; j < 16; ++j) {
            const float a = acc[j];
            if (__any(a > k2)) {
                const int m = mbase + (j & 3) + 8 * (j >> 2);
                const bool g0 = a > k0, g1 = a > k1, g2 = a > k2;
                k2 = g1 ? k1 : (g2 ? a : k2); i2 = g1 ? i1 : (g2 ? m : i2);
                k1 = g0 ? k0 : (g1 ? a : k1); i1 = g0 ? i0 : (g1 ? m : i1);
                k0 = g0 ? a : k0;             i0 = g0 ? m : i0;
            }
        }
    }

    const float ok[3] = {__shfl_xor(k0, 32), __shfl_xor(k1, 32), __shfl_xor(k2, 32)};
    const int oi[3] = {__shfl_xor(i0, 32), __shfl_xor(i1, 32), __shfl_xor(i2, 32)};
#pragma unroll
    for (int r = 0; r < 3; ++r) {
        const float ck = ok[r]; const int ci = oi[r];
        const bool b0 = (ck > k0) || (ck == k0 && ci < i0);
        const bool b1 = (ck > k1) || (ck == k1 && ci < i1);
        const bool b2 = (ck > k2) || (ck == k2 && ci < i2);
        k2 = b1 ? k1 : (b2 ? ck : k2); i2 = b1 ? i1 : (b2 ? ci : i2);
        k1 = b0 ? k0 : (b1 ? ck : k1); i1 = b0 ? i0 : (b1 ? ci : i1);
        k0 = b0 ? ck : k0;             i0 = b0 ? ci : i0;
    }
    if (lane < 32) {
        const int q = qg * 32 + lane;
        const size_t o = (((size_t)b * SPL + s) * NN + q) * 3;
        pd[o] = -2.0f * k0; pd[o + 1] = -2.0f * k1; pd[o + 2] = -2.0f * k2;
        pi[o] = i0; pi[o + 1] = i1; pi[o + 2] = i2;
    }
}

// ---------------------------------------------------------------------------
// K3: merge SPL sorted top-3 lists, (key, idx) lexicographic; fully unrolled.
// ---------------------------------------------------------------------------
__global__ __launch_bounds__(256) void k_merge(const float* __restrict__ pd,
                                               const int* __restrict__ pi,
                                               int* __restrict__ fi) {
    const int t = blockIdx.x * 256 + threadIdx.x;
    if (t >= BB * NN) return;
    const int b = t / NN, n = t % NN;
    float dv[3 * SPL]; int iv[3 * SPL];
#pragma unroll
    for (int s = 0; s < SPL; ++s) {
        const size_t o = (((size_t)b * SPL + s) * NN + n) * 3;
#pragma unroll
        for (int r = 0; r < 3; ++r) {
            dv[s * 3 + r] = pd[o + r];
            iv[s * 3 + r] = pi[o + r];
        }
    }
    float bd = -FLT_MAX; int bi = -1;
#pragma unroll
    for (int r = 0; r < 3; ++r) {
        float cd = FLT_MAX; int ci = 0x7fffffff;
#pragma unroll
        for (int j = 0; j < 3 * SPL; ++j) {
            const bool gt_prev = (dv[j] > bd) || (dv[j] == bd && iv[j] > bi);
            const bool lt_cur = (dv[j] < cd) || (dv[j] == cd && iv[j] < ci);
            if (gt_prev && lt_cur) { cd = dv[j]; ci = iv[j]; }
        }
        fi[(size_t)t * 3 + r] = ci;
        bd = cd; bi = ci;
    }
}

// ---------------------------------------------------------------------------
// K4: MFMA conv. Block = 64 points x 64 co, 4 waves: wave w -> mtile = w>>1
// (32 points), ct2 = w&1 (co half). A = gathered hi-fp16 fragments straight
// from xe (kb 0..3), B = pre-packed Wf. 12 MFMA + 12 gathers per wave.
// Epilogue: bias + relu -> padded LDS transpose -> 256B-coalesced stores.
// ---------------------------------------------------------------------------
__global__ __launch_bounds__(256) void k_conv(const uint4* __restrict__ xe,
                                              const uint4* __restrict__ Wf,
                                              const int* __restrict__ fi,
                                              const float* __restrict__ bias,
                                              float* __restrict__ out) {
    __shared__ float ot[64][65];
    const int b = blockIdx.y;
    const int n0 = blockIdx.x * 64;
    const int tid = threadIdx.x;
    const int l = tid & 63;
    const int w = tid >> 6;
    const int mt = w >> 1, ct2 = w & 1;
    const int p31 = l & 31, kh = l >> 5;
    const int npt = n0 + mt * 32 + p31;

    f32x16 acc = {};
    const uint4* xb = xe + (size_t)b * 64 * 8 * 64;
    const int fbase3 = (b * NN + npt) * KNN;
#pragma unroll
    for (int kk = 0; kk < KNN; ++kk) {
        const int src = fi[fbase3 + kk];
        const uint4* ap = xb + (size_t)(src >> 5) * 512 + (src & 31) + 32 * kh;
        uint4 af[4], bw[4];
#pragma unroll
        for (int kb = 0; kb < 4; ++kb) af[kb] = ap[(size_t)kb * 64];
#pragma unroll
        for (int kb = 0; kb < 4; ++kb) bw[kb] = Wf[((kk * 2 + ct2) * 4 + kb) * 64 + l];
#pragma unroll
        for (int kb = 0; kb < 4; ++kb) {
            union { uint4 v; half8 h; } ua, ub;
            ua.v = af[kb]; ub.v = bw[kb];
            acc = __builtin_amdgcn_mfma_f32_32x32x16_f16(ua.h, ub.h, acc, 0, 0, 0);
        }
    }
    const int co = ct2 * 32 + p31;
    const float bv = bias[co];
#pragma unroll
    for (int j = 0; j < 16; ++j) {
        const int pt = mt * 32 + (j & 3) + 8 * (j >> 2) + 4 * kh;
        ot[co][pt] = fmaxf(acc[j] + bv, 0.f);
    }
    __syncthreads();
#pragma unroll
    for (int i = 0; i < 16; ++i) {
        const int v = tid + 256 * i;
        const int co2 = v >> 6, col = v & 63;
        out[((size_t)(b * COUT + co2)) * NN + n0 + col] = ot[co2][col];
    }
}

extern "C" void kernel_launch(void* const* d_in, const int* in_sizes, int n_in,
                              void* d_out, int out_size, void* d_ws, size_t ws_size,
                              hipStream_t stream) {
    const float* x = (const float*)d_in[0];
    const float* W = (const float*)d_in[1];
    const float* bias = (const float*)d_in[2];
    float* out = (float*)d_out;

    char* ws = (char*)d_ws;
    uint4* xe = (uint4*)(ws);                       //  8,388,608 B
    unsigned* anc = (unsigned*)(ws + 8388608);      //    262,144 B
    uint4* Wf = (uint4*)(ws + 8650752);             //     24,576 B
    float* pd = (float*)(ws + 8675328);             //  1,572,864 B
    int* pi = (int*)(ws + 10248192);                //  1,572,864 B
    int* fi = (int*)(ws + 11821056);                //    393,216 B (end ~12.2 MB)

    k_prep<<<dim3(BB, NN / 64), 256, 0, stream>>>(x, xe, anc);
    k_wprep<<<1, 256, 0, stream>>>(W, Wf);
    k_top3<<<dim3(16, SPL, BB), 256, 0, stream>>>((const half8*)xe, anc, pd, pi);
    k_merge<<<(BB * NN + 255) / 256, 256, 0, stream>>>(pd, pi, fi);
    k_conv<<<dim3(NN / 64, BB), 256, 0, stream>>>(xe, Wf, fi, bias, out);
}